// Round 4
// baseline (112.052 us; speedup 1.0000x reference)
//
#include <hip/hip_runtime.h>

typedef __attribute__((ext_vector_type(8))) short short8;
typedef __attribute__((ext_vector_type(4))) float floatx4;

#define BS   32768
#define NIN  512
#define NE   8
#define NH   256

__device__ __forceinline__ unsigned short f2bf(float f) {
  unsigned int u = __float_as_uint(f);
  u += 0x7fffu + ((u >> 16) & 1u);   // round-to-nearest-even
  return (unsigned short)(u >> 16);
}

// Transpose We [8][512][256] f32 -> WeT [8][256][512] bf16 (k-contiguous rows)
__global__ void prep_weT(const float* __restrict__ We, unsigned short* __restrict__ WeT) {
  int e  = blockIdx.x >> 6;
  int kc = blockIdx.x & 63;
  int h  = threadIdx.x;
  short8 pk;
#pragma unroll
  for (int j = 0; j < 8; ++j)
    pk[j] = (short)f2bf(We[e * 131072 + (kc * 8 + j) * 256 + h]);
  *reinterpret_cast<short8*>(&WeT[e * 131072 + h * 512 + kc * 8]) = pk;
}

// Wg [2][512][8] f32 -> WgT [16][512] bf16, row = t*8+e
__global__ void prep_wgT(const float* __restrict__ Wg, unsigned short* __restrict__ WgT) {
  int row = blockIdx.x;
  int t = row >> 3, e = row & 7;
  int lane = threadIdx.x;
  short8 pk;
#pragma unroll
  for (int j = 0; j < 8; ++j)
    pk[j] = (short)f2bf(Wg[t * 4096 + (lane * 8 + j) * 8 + e]);
  *reinterpret_cast<short8*>(&WgT[row * 512 + lane * 8]) = pk;
}

#define GLOAD16(SRC, DST) \
  __builtin_amdgcn_global_load_lds( \
      (const __attribute__((address_space(1))) unsigned int*)(SRC), \
      (__attribute__((address_space(3))) unsigned int*)(DST), 16, 0, 0)

// 512 thr = 8 waves, grid 2m x 4n. Wave tile 32m x 64n. A (full K) in registers
// (128 VGPR/lane). B double-buffered in LDS via global_load_lds; counted-vmcnt
// two-barrier phases (m201 T3+T4): 8 loads stay in flight across barriers.
__global__ __launch_bounds__(512, 1) void mmoe_main(
    const float* __restrict__ xv,            // [32768,512]
    const unsigned short* __restrict__ WeT,  // [8][256][512] bf16
    const unsigned short* __restrict__ WgT,  // [16][512] bf16
    const float* __restrict__ be,            // [8][256]
    const float* __restrict__ bg,            // [2][8]
    const float* __restrict__ Wt,            // [2][256]
    const float* __restrict__ bt,            // [2]
    float* __restrict__ out)                 // [2][32768]
{
  __shared__ __attribute__((aligned(16))) unsigned char smem[131072]; // buf0 | buf1 (buf1 doubles as A transient)
  __shared__ float gates_lds[64][17];
  __shared__ float red_lds[8][32][2];
  __shared__ float be_lds[2048];             // [8][256]

  const int tid   = threadIdx.x;
  const int wave  = tid >> 6;
  const int lane  = tid & 63;
  const int row16 = lane & 15;
  const int kgrp  = lane >> 4;
  const int wm    = wave >> 2;   // 0..1
  const int wn    = wave & 3;    // 0..3
  const int b0    = blockIdx.x * 64;

  unsigned char* buf0 = smem;
  unsigned char* bufA = smem + 65536;  // == buf1

  // ---- prologue: stage(0) -> buf0 (pre-swizzled source) ----
#pragma unroll
  for (int i = 0; i < 8; ++i) {
    unsigned x = (unsigned)(i * 8192 + tid * 16);
    unsigned r = x >> 8;
    unsigned y = (x & 255u) ^ ((r & 15u) << 4);
    const unsigned short* src = WeT + ((int)r * 512 + (int)(y >> 1));
    GLOAD16(src, buf0 + (i * 8 + wave) * 1024);
  }

  // ---- A tile (64 x 512) fp32->bf16 into bufA, swizzled (byte ^= (r&7)<<4) ----
#pragma unroll
  for (int i = 0; i < 8; ++i) {
    int idx = i * 512 + tid;
    int r = idx >> 6, c = idx & 63;
    const float4* src = reinterpret_cast<const float4*>(xv + (size_t)(b0 + r) * 512 + c * 8);
    float4 v0 = src[0];
    float4 v1 = src[1];
    short8 pk;
    pk[0] = (short)f2bf(v0.x); pk[1] = (short)f2bf(v0.y);
    pk[2] = (short)f2bf(v0.z); pk[3] = (short)f2bf(v0.w);
    pk[4] = (short)f2bf(v1.x); pk[5] = (short)f2bf(v1.y);
    pk[6] = (short)f2bf(v1.z); pk[7] = (short)f2bf(v1.w);
    unsigned addr = ((unsigned)(r << 10) + (unsigned)(c << 4)) ^ (unsigned)((r & 7) << 4);
    *reinterpret_cast<short8*>(&bufA[addr]) = pk;
  }

  // be -> LDS (epilogue reads via lgkm, keeps vmcnt math exact in main loop)
#pragma unroll
  for (int j = 0; j < 4; ++j) {
    int idx = j * 512 + tid;
    be_lds[idx] = be[idx];
  }

  __syncthreads();   // full drain: stage(0) + A writes + be done (one-time)

  // ---- gates: waves 0..3 compute m-frag `wave`; softmax over experts ----
  if (wave < 4) {
    floatx4 gacc = {0.f, 0.f, 0.f, 0.f};
    const unsigned abase = ((unsigned)row16 << 10) + ((unsigned)kgrp << 4) + ((unsigned)wave << 14);
    const unsigned a_swz = (unsigned)((row16 & 7) << 4);
    const unsigned short* wg_lane = WgT + row16 * 512 + kgrp * 8;
#pragma unroll
    for (int ks = 0; ks < 16; ++ks) {
      short8 af = *reinterpret_cast<const short8*>(&bufA[(abase + (unsigned)(ks << 6)) ^ a_swz]);
      short8 bf = *reinterpret_cast<const short8*>(wg_lane + ks * 32);
      gacc = __builtin_amdgcn_mfma_f32_16x16x32_bf16(af, bf, gacc, 0, 0, 0);
    }
    float bgv = bg[row16];
#pragma unroll
    for (int j = 0; j < 4; ++j) {
      float v = gacc[j] + bgv;
      float mx = v;
      mx = fmaxf(mx, __shfl_xor(mx, 1));
      mx = fmaxf(mx, __shfl_xor(mx, 2));
      mx = fmaxf(mx, __shfl_xor(mx, 4));
      float p = __expf(v - mx);
      float s = p;
      s += __shfl_xor(s, 1);
      s += __shfl_xor(s, 2);
      s += __shfl_xor(s, 4);
      gates_lds[wave * 16 + kgrp * 4 + j][row16] = p / s;
    }
  }

  // ---- A-reg fill: 2 m-frags x 16 k-chunks per lane (128 VGPRs) ----
  short8 a_reg[2][16];
  {
    const unsigned a_swz = (unsigned)((row16 & 7) << 4);
#pragma unroll
    for (int m2 = 0; m2 < 2; ++m2) {
      const unsigned rbase = (unsigned)((wm * 2 + m2) * 16 + row16) << 10;
#pragma unroll
      for (int c = 0; c < 16; ++c)
        a_reg[m2][c] = *reinterpret_cast<const short8*>(
            &bufA[rbase + (((unsigned)(c << 6) + ((unsigned)kgrp << 4)) ^ a_swz)]);
    }
  }

  float wtv[2][4];
#pragma unroll
  for (int t = 0; t < 2; ++t)
#pragma unroll
    for (int n = 0; n < 4; ++n)
      wtv[t][n] = Wt[t * 256 + wn * 64 + n * 16 + row16];

  __syncthreads();   // A-reg fill + gates done; bufA free as B buffer

  // ---- main loop: 32 phases (8e x 4kc); counted vmcnt, 2 barriers/phase ----
  float outacc[2][4][2];
#pragma unroll
  for (int m = 0; m < 2; ++m)
#pragma unroll
    for (int j = 0; j < 4; ++j) { outacc[m][j][0] = 0.f; outacc[m][j][1] = 0.f; }

  const unsigned b_swz = (unsigned)(row16 << 4);
  const unsigned b_col = (unsigned)(wn * 64 + row16);

  for (int e = 0; e < 8; ++e) {
    floatx4 acc[2][4];
#pragma unroll
    for (int m = 0; m < 2; ++m)
#pragma unroll
      for (int n = 0; n < 4; ++n) acc[m][n] = (floatx4){0.f, 0.f, 0.f, 0.f};

#pragma unroll
    for (int kc = 0; kc < 4; ++kc) {
      const int p = e * 4 + kc;
      // 1. issue stage(p+1) into buf[(p+1)&1]  (safe: last read in p-1, barrier#2'd)
      if (p < 31) {
        unsigned char* sbuf = (p & 1) ? buf0 : bufA;
        const int ne  = (kc < 3) ? e : e + 1;
        const int nkc = (kc + 1) & 3;
#pragma unroll
        for (int i = 0; i < 8; ++i) {
          unsigned x = (unsigned)(i * 8192 + tid * 16);
          unsigned r = x >> 8;
          unsigned y = (x & 255u) ^ ((r & 15u) << 4);
          const unsigned short* src = WeT + ((ne * 256 + (int)r) * 512 + nkc * 128 + (int)(y >> 1));
          GLOAD16(src, sbuf + (i * 8 + wave) * 1024);
        }
        __builtin_amdgcn_sched_barrier(0);
        asm volatile("s_waitcnt vmcnt(8)" ::: "memory");   // own stage(p) done; stage(p+1) stays in flight
      } else {
        asm volatile("s_waitcnt vmcnt(0)" ::: "memory");   // final phase
      }
      __builtin_amdgcn_sched_barrier(0);
      __builtin_amdgcn_s_barrier();                        // all waves' stage(p) complete
      __builtin_amdgcn_sched_barrier(0);

      // 2. consume buf[p&1]
      const unsigned char* cb = (p & 1) ? bufA : buf0;
      __builtin_amdgcn_s_setprio(1);
#pragma unroll
      for (int ks = 0; ks < 4; ++ks) {
        short8 bfv[4];
#pragma unroll
        for (int n = 0; n < 4; ++n) {
          unsigned col = b_col + (unsigned)(n * 16);
          unsigned kb  = ((unsigned)(ks * 64 + kgrp * 16)) ^ b_swz;
          bfv[n] = *reinterpret_cast<const short8*>(&cb[col * 256 + kb]);
        }
#pragma unroll
        for (int m2 = 0; m2 < 2; ++m2)
#pragma unroll
          for (int n = 0; n < 4; ++n)
            acc[m2][n] = __builtin_amdgcn_mfma_f32_16x16x32_bf16(
                a_reg[m2][kc * 4 + ks], bfv[n], acc[m2][n], 0, 0, 0);
      }
      __builtin_amdgcn_s_setprio(0);
      __builtin_amdgcn_sched_barrier(0);
      __builtin_amdgcn_s_barrier();                        // all reads of buf[p&1] done
      __builtin_amdgcn_sched_barrier(0);
    }

    // ---- expert epilogue: bias+relu -> Wt-dot -> gate-weighted accumulate (LDS only) ----
    float bev[4];
#pragma unroll
    for (int n = 0; n < 4; ++n)
      bev[n] = be_lds[e * 256 + wn * 64 + n * 16 + row16];

#pragma unroll
    for (int m2 = 0; m2 < 2; ++m2) {
#pragma unroll
      for (int j = 0; j < 4; ++j) {
        int row = (wm * 2 + m2) * 16 + kgrp * 4 + j;
        float p0 = 0.f, p1 = 0.f;
#pragma unroll
        for (int n = 0; n < 4; ++n) {
          float r = fmaxf(acc[m2][n][j] + bev[n], 0.f);
          p0 = fmaf(r, wtv[0][n], p0);
          p1 = fmaf(r, wtv[1][n], p1);
        }
        outacc[m2][j][0] = fmaf(gates_lds[row][e],     p0, outacc[m2][j][0]);
        outacc[m2][j][1] = fmaf(gates_lds[row][8 + e], p1, outacc[m2][j][1]);
      }
    }
  }

  // ---- reduce over 16 col-lanes, then across the 4 n-waves via LDS ----
#pragma unroll
  for (int m = 0; m < 2; ++m)
#pragma unroll
    for (int j = 0; j < 4; ++j)
#pragma unroll
      for (int t = 0; t < 2; ++t) {
        float v = outacc[m][j][t];
        v += __shfl_xor(v, 1);
        v += __shfl_xor(v, 2);
        v += __shfl_xor(v, 4);
        v += __shfl_xor(v, 8);
        outacc[m][j][t] = v;
      }
  if (row16 == 0) {
#pragma unroll
    for (int m = 0; m < 2; ++m)
#pragma unroll
      for (int j = 0; j < 4; ++j) {
        int lr = m * 16 + kgrp * 4 + j;
        red_lds[wave][lr][0] = outacc[m][j][0];
        red_lds[wave][lr][1] = outacc[m][j][1];
      }
  }
  __syncthreads();

  if (tid < 128) {
    int row = tid >> 1, t = tid & 1;
    int wmr = row >> 5, lr = row & 31;
    float s = red_lds[wmr * 4 + 0][lr][t] + red_lds[wmr * 4 + 1][lr][t]
            + red_lds[wmr * 4 + 2][lr][t] + red_lds[wmr * 4 + 3][lr][t];
    s += bt[t];
    s = fmaxf(s, 0.f);
    out[t * BS + b0 + row] = 1.f / (1.f + __expf(-s));
  }
}

extern "C" void kernel_launch(void* const* d_in, const int* in_sizes, int n_in,
                              void* d_out, int out_size, void* d_ws, size_t ws_size,
                              hipStream_t stream) {
  const float* xv = (const float*)d_in[0];
  const float* We = (const float*)d_in[1];
  const float* be = (const float*)d_in[2];
  const float* Wg = (const float*)d_in[3];
  const float* bg = (const float*)d_in[4];
  const float* Wt = (const float*)d_in[5];
  const float* bt = (const float*)d_in[6];
  float* out = (float*)d_out;

  unsigned short* WeT = (unsigned short*)d_ws;            // 2 MiB
  unsigned short* WgT = WeT + 8 * 256 * 512;              // 16 KiB

  prep_weT<<<512, 256, 0, stream>>>(We, WeT);
  prep_wgT<<<16, 64, 0, stream>>>(Wg, WgT);
  mmoe_main<<<512, 512, 0, stream>>>(xv, WeT, WgT, be, bg, Wt, bt, out);
}

// Round 6
// 110.083 us; speedup vs baseline: 1.0179x; 1.0179x over previous
//
#include <hip/hip_runtime.h>

typedef __attribute__((ext_vector_type(8))) short short8;
typedef __attribute__((ext_vector_type(4))) float floatx4;

#define BS   32768
#define NIN  512
#define NE   8
#define NH   256

__device__ __forceinline__ unsigned short f2bf(float f) {
  unsigned int u = __float_as_uint(f);
  u += 0x7fffu + ((u >> 16) & 1u);   // round-to-nearest-even
  return (unsigned short)(u >> 16);
}

// Transpose We [8][512][256] f32 -> WeT [8][256][512] bf16 (k-contiguous rows)
__global__ void prep_weT(const float* __restrict__ We, unsigned short* __restrict__ WeT) {
  int e  = blockIdx.x >> 6;
  int kc = blockIdx.x & 63;
  int h  = threadIdx.x;
  short8 pk;
#pragma unroll
  for (int j = 0; j < 8; ++j)
    pk[j] = (short)f2bf(We[e * 131072 + (kc * 8 + j) * 256 + h]);
  *reinterpret_cast<short8*>(&WeT[e * 131072 + h * 512 + kc * 8]) = pk;
}

// Wg [2][512][8] f32 -> WgT [16][512] bf16, row = t*8+e
__global__ void prep_wgT(const float* __restrict__ Wg, unsigned short* __restrict__ WgT) {
  int row = blockIdx.x;
  int t = row >> 3, e = row & 7;
  int lane = threadIdx.x;
  short8 pk;
#pragma unroll
  for (int j = 0; j < 8; ++j)
    pk[j] = (short)f2bf(Wg[t * 4096 + (lane * 8 + j) * 8 + e]);
  *reinterpret_cast<short8*>(&WgT[row * 512 + lane * 8]) = pk;
}

#define GLOAD16(SRC, DST) \
  __builtin_amdgcn_global_load_lds( \
      (const __attribute__((address_space(1))) unsigned int*)(SRC), \
      (__attribute__((address_space(3))) unsigned int*)(DST), 16, 0, 0)

// 512 thr = 8 waves, grid 2m x 4n. Wave tile 32m x 64n. A (full K) in registers
// (128 VGPR/lane). B double-buffered in LDS via global_load_lds; counted-vmcnt
// two-barrier phases. v6: fix staged-chunk k offset (nkc*128, was nkc*64).
__global__ __launch_bounds__(512, 2) void mmoe_main(
    const float* __restrict__ xv,            // [32768,512]
    const unsigned short* __restrict__ WeT,  // [8][256][512] bf16
    const unsigned short* __restrict__ WgT,  // [16][512] bf16
    const float* __restrict__ be,            // [8][256]
    const float* __restrict__ bg,            // [2][8]
    const float* __restrict__ Wt,            // [2][256]
    const float* __restrict__ bt,            // [2]
    float* __restrict__ out)                 // [2][32768]
{
  __shared__ __attribute__((aligned(16))) unsigned char smem[131072]; // buf0 | buf1 (buf1 doubles as A transient)
  __shared__ float gates_lds[64][17];
  __shared__ float red_lds[8][32][2];
  __shared__ float be_lds[2048];             // [8][256]

  const int tid   = threadIdx.x;
  const int wave  = tid >> 6;
  const int lane  = tid & 63;
  const int row16 = lane & 15;
  const int kgrp  = lane >> 4;
  const int wm    = wave >> 2;   // 0..1
  const int wn    = wave & 3;    // 0..3
  const int b0    = blockIdx.x * 64;

  unsigned char* buf0 = smem;
  unsigned char* bufA = smem + 65536;  // == buf1

  // ---- hoisted stage addressing: element offset into WeT (per i) ----
  unsigned soff[8];
#pragma unroll
  for (int i = 0; i < 8; ++i) {
    unsigned x = (unsigned)(i * 8192 + tid * 16);
    unsigned r = x >> 8;
    unsigned y = (x & 255u) ^ ((r & 15u) << 4);
    soff[i] = r * 512u + (y >> 1);     // pre-swizzled source element offset
  }

  // ---- prologue: stage(0) -> buf0 ----
#pragma unroll
  for (int i = 0; i < 8; ++i)
    GLOAD16(WeT + soff[i], buf0 + (i * 8 + wave) * 1024);

  // ---- A tile (64 x 512) fp32->bf16 into bufA, swizzled (byte ^= (r&7)<<4) ----
#pragma unroll
  for (int i = 0; i < 8; ++i) {
    int idx = i * 512 + tid;
    int r = idx >> 6, c = idx & 63;
    const float4* src = reinterpret_cast<const float4*>(xv + (size_t)(b0 + r) * 512 + c * 8);
    float4 v0 = src[0];
    float4 v1 = src[1];
    short8 pk;
    pk[0] = (short)f2bf(v0.x); pk[1] = (short)f2bf(v0.y);
    pk[2] = (short)f2bf(v0.z); pk[3] = (short)f2bf(v0.w);
    pk[4] = (short)f2bf(v1.x); pk[5] = (short)f2bf(v1.y);
    pk[6] = (short)f2bf(v1.z); pk[7] = (short)f2bf(v1.w);
    unsigned addr = ((unsigned)(r << 10) + (unsigned)(c << 4)) ^ (unsigned)((r & 7) << 4);
    *reinterpret_cast<short8*>(&bufA[addr]) = pk;
  }

  // be -> LDS (epilogue reads via lgkm; keeps main-loop vmcnt math exact)
#pragma unroll
  for (int j = 0; j < 4; ++j) {
    int idx = j * 512 + tid;
    be_lds[idx] = be[idx];
  }

  __syncthreads();   // full drain: stage(0) + A writes + be done (one-time)

  // ---- gates: waves 0..3 compute m-frag `wave`; softmax over experts ----
  if (wave < 4) {
    floatx4 gacc = {0.f, 0.f, 0.f, 0.f};
    const unsigned abase = ((unsigned)row16 << 10) + ((unsigned)kgrp << 4) + ((unsigned)wave << 14);
    const unsigned a_swz = (unsigned)((row16 & 7) << 4);
    const unsigned short* wg_lane = WgT + row16 * 512 + kgrp * 8;
#pragma unroll
    for (int ks = 0; ks < 16; ++ks) {
      short8 af = *reinterpret_cast<const short8*>(&bufA[(abase + (unsigned)(ks << 6)) ^ a_swz]);
      short8 bf = *reinterpret_cast<const short8*>(wg_lane + ks * 32);
      gacc = __builtin_amdgcn_mfma_f32_16x16x32_bf16(af, bf, gacc, 0, 0, 0);
    }
    float bgv = bg[row16];
#pragma unroll
    for (int j = 0; j < 4; ++j) {
      float v = gacc[j] + bgv;
      float mx = v;
      mx = fmaxf(mx, __shfl_xor(mx, 1));
      mx = fmaxf(mx, __shfl_xor(mx, 2));
      mx = fmaxf(mx, __shfl_xor(mx, 4));
      float p = __expf(v - mx);
      float s = p;
      s += __shfl_xor(s, 1);
      s += __shfl_xor(s, 2);
      s += __shfl_xor(s, 4);
      gates_lds[wave * 16 + kgrp * 4 + j][row16] = p / s;
    }
  }

  // ---- A-reg fill: 2 m-frags x 16 k-chunks per lane (128 VGPRs) ----
  short8 a_reg[2][16];
  {
    const unsigned a_swz = (unsigned)((row16 & 7) << 4);
#pragma unroll
    for (int m2 = 0; m2 < 2; ++m2) {
      const unsigned rbase = (unsigned)((wm * 2 + m2) * 16 + row16) << 10;
#pragma unroll
      for (int c = 0; c < 16; ++c)
        a_reg[m2][c] = *reinterpret_cast<const short8*>(
            &bufA[rbase + (((unsigned)(c << 6) + ((unsigned)kgrp << 4)) ^ a_swz)]);
    }
  }

  float wtv[2][4];
#pragma unroll
  for (int t = 0; t < 2; ++t)
#pragma unroll
    for (int n = 0; n < 4; ++n)
      wtv[t][n] = Wt[t * 256 + wn * 64 + n * 16 + row16];

  __syncthreads();   // A-reg fill + gates done; bufA free as B buffer

  // ---- main loop: 32 phases (8e x 4kc); counted vmcnt, 2 barriers/phase ----
  float outacc[2][4][2];
#pragma unroll
  for (int m = 0; m < 2; ++m)
#pragma unroll
    for (int j = 0; j < 4; ++j) { outacc[m][j][0] = 0.f; outacc[m][j][1] = 0.f; }

  const unsigned b_swz = (unsigned)(row16 << 4);
  const unsigned b_col = (unsigned)(wn * 64 + row16);

  for (int e = 0; e < 8; ++e) {
    floatx4 acc[2][4];
#pragma unroll
    for (int m = 0; m < 2; ++m)
#pragma unroll
      for (int n = 0; n < 4; ++n) acc[m][n] = (floatx4){0.f, 0.f, 0.f, 0.f};

#pragma unroll
    for (int kc = 0; kc < 4; ++kc) {
      const int p = e * 4 + kc;
      // 1. issue stage(p+1) into buf[(p+1)&1]
      if (p < 31) {
        unsigned char* sbuf = (p & 1) ? buf0 : bufA;
        const int ne  = (kc < 3) ? e : e + 1;
        const int nkc = (kc + 1) & 3;
        const unsigned short* base = WeT + (ne * 131072 + nkc * 128);  // k-chunk = 128 elements
#pragma unroll
        for (int i = 0; i < 8; ++i)
          GLOAD16(base + soff[i], sbuf + (i * 8 + wave) * 1024);
        asm volatile("s_waitcnt vmcnt(8)" ::: "memory");   // own stage(p) done; stage(p+1) in flight
      } else {
        asm volatile("s_waitcnt vmcnt(0)" ::: "memory");   // final phase
      }
      __builtin_amdgcn_s_barrier();                        // all waves' stage(p) complete
      __builtin_amdgcn_sched_barrier(0);                   // keep ds_reads below the barrier

      // 2. consume buf[p&1]
      const unsigned char* cb = (p & 1) ? bufA : buf0;
      __builtin_amdgcn_s_setprio(1);
#pragma unroll
      for (int ks = 0; ks < 4; ++ks) {
        short8 bfv[4];
#pragma unroll
        for (int n = 0; n < 4; ++n) {
          unsigned col = b_col + (unsigned)(n * 16);
          unsigned kb  = ((unsigned)(ks * 64 + kgrp * 16)) ^ b_swz;
          bfv[n] = *reinterpret_cast<const short8*>(&cb[col * 256 + kb]);
        }
#pragma unroll
        for (int m2 = 0; m2 < 2; ++m2)
#pragma unroll
          for (int n = 0; n < 4; ++n)
            acc[m2][n] = __builtin_amdgcn_mfma_f32_16x16x32_bf16(
                a_reg[m2][kc * 4 + ks], bfv[n], acc[m2][n], 0, 0, 0);
      }
      __builtin_amdgcn_s_setprio(0);
      __builtin_amdgcn_s_barrier();                        // all reads of buf[p&1] done
    }

    // ---- expert epilogue: bias+relu -> Wt-dot -> gate-weighted accumulate (LDS only) ----
    float bev[4];
#pragma unroll
    for (int n = 0; n < 4; ++n)
      bev[n] = be_lds[e * 256 + wn * 64 + n * 16 + row16];

#pragma unroll
    for (int m2 = 0; m2 < 2; ++m2) {
#pragma unroll
      for (int j = 0; j < 4; ++j) {
        int row = (wm * 2 + m2) * 16 + kgrp * 4 + j;
        float p0 = 0.f, p1 = 0.f;
#pragma unroll
        for (int n = 0; n < 4; ++n) {
          float r = fmaxf(acc[m2][n][j] + bev[n], 0.f);
          p0 = fmaf(r, wtv[0][n], p0);
          p1 = fmaf(r, wtv[1][n], p1);
        }
        outacc[m2][j][0] = fmaf(gates_lds[row][e],     p0, outacc[m2][j][0]);
        outacc[m2][j][1] = fmaf(gates_lds[row][8 + e], p1, outacc[m2][j][1]);
      }
    }
  }

  // ---- reduce over 16 col-lanes, then across the 4 n-waves via LDS ----
#pragma unroll
  for (int m = 0; m < 2; ++m)
#pragma unroll
    for (int j = 0; j < 4; ++j)
#pragma unroll
      for (int t = 0; t < 2; ++t) {
        float v = outacc[m][j][t];
        v += __shfl_xor(v, 1);
        v += __shfl_xor(v, 2);
        v += __shfl_xor(v, 4);
        v += __shfl_xor(v, 8);
        outacc[m][j][t] = v;
      }
  if (row16 == 0) {
#pragma unroll
    for (int m = 0; m < 2; ++m)
#pragma unroll
      for (int j = 0; j < 4; ++j) {
        int lr = m * 16 + kgrp * 4 + j;
        red_lds[wave][lr][0] = outacc[m][j][0];
        red_lds[wave][lr][1] = outacc[m][j][1];
      }
  }
  __syncthreads();

  if (tid < 128) {
    int row = tid >> 1, t = tid & 1;
    int wmr = row >> 5, lr = row & 31;
    float s = red_lds[wmr * 4 + 0][lr][t] + red_lds[wmr * 4 + 1][lr][t]
            + red_lds[wmr * 4 + 2][lr][t] + red_lds[wmr * 4 + 3][lr][t];
    s += bt[t];
    s = fmaxf(s, 0.f);
    out[t * BS + b0 + row] = 1.f / (1.f + __expf(-s));
  }
}

extern "C" void kernel_launch(void* const* d_in, const int* in_sizes, int n_in,
                              void* d_out, int out_size, void* d_ws, size_t ws_size,
                              hipStream_t stream) {
  const float* xv = (const float*)d_in[0];
  const float* We = (const float*)d_in[1];
  const float* be = (const float*)d_in[2];
  const float* Wg = (const float*)d_in[3];
  const float* bg = (const float*)d_in[4];
  const float* Wt = (const float*)d_in[5];
  const float* bt = (const float*)d_in[6];
  float* out = (float*)d_out;

  unsigned short* WeT = (unsigned short*)d_ws;            // 2 MiB
  unsigned short* WgT = WeT + 8 * 256 * 512;              // 16 KiB

  prep_weT<<<512, 256, 0, stream>>>(We, WeT);
  prep_wgT<<<16, 64, 0, stream>>>(Wg, WgT);
  mmoe_main<<<512, 512, 0, stream>>>(xv, WeT, WgT, be, bg, Wt, bt, out);
}

// Round 7
// 107.388 us; speedup vs baseline: 1.0434x; 1.0251x over previous
//
#include <hip/hip_runtime.h>

typedef __attribute__((ext_vector_type(8))) short short8;
typedef __attribute__((ext_vector_type(4))) float floatx4;
typedef __attribute__((ext_vector_type(4))) float f32x4;

#define BS   32768
#define NIN  512
#define NE   8
#define NH   256

__device__ __forceinline__ unsigned short f2bf(float f) {
  unsigned int u = __float_as_uint(f);
  u += 0x7fffu + ((u >> 16) & 1u);   // round-to-nearest-even
  return (unsigned short)(u >> 16);
}

// Transpose We [8][512][256] f32 -> WeT [8][256][512] bf16 (k-contiguous rows)
__global__ void prep_weT(const float* __restrict__ We, unsigned short* __restrict__ WeT) {
  int e  = blockIdx.x >> 6;
  int kc = blockIdx.x & 63;
  int h  = threadIdx.x;
  short8 pk;
#pragma unroll
  for (int j = 0; j < 8; ++j)
    pk[j] = (short)f2bf(We[e * 131072 + (kc * 8 + j) * 256 + h]);
  *reinterpret_cast<short8*>(&WeT[e * 131072 + h * 512 + kc * 8]) = pk;
}

// Wg [2][512][8] f32 -> WgT [16][512] bf16, row = t*8+e
__global__ void prep_wgT(const float* __restrict__ Wg, unsigned short* __restrict__ WgT) {
  int row = blockIdx.x;
  int t = row >> 3, e = row & 7;
  int lane = threadIdx.x;
  short8 pk;
#pragma unroll
  for (int j = 0; j < 8; ++j)
    pk[j] = (short)f2bf(Wg[t * 4096 + (lane * 8 + j) * 8 + e]);
  *reinterpret_cast<short8*>(&WgT[row * 512 + lane * 8]) = pk;
}

#define GLOAD16(SRC, DST) \
  __builtin_amdgcn_global_load_lds( \
      (const __attribute__((address_space(1))) unsigned int*)(SRC), \
      (__attribute__((address_space(3))) unsigned int*)(DST), 16, 0, 0)

// 512 thr = 8 waves, grid 2m x 4n. Wave tile 32m x 64n. A (full K) in registers
// (128 VGPR/lane). B double-buffered in LDS via global_load_lds; counted-vmcnt
// two-barrier phases. v7: xv loads NON-TEMPORAL so streaming A doesn't evict
// the 2MB WeT from per-XCD L2 (B re-reads = 1GB/dispatch must stay L2-local).
__global__ __launch_bounds__(512, 2) void mmoe_main(
    const float* __restrict__ xv,            // [32768,512]
    const unsigned short* __restrict__ WeT,  // [8][256][512] bf16
    const unsigned short* __restrict__ WgT,  // [16][512] bf16
    const float* __restrict__ be,            // [8][256]
    const float* __restrict__ bg,            // [2][8]
    const float* __restrict__ Wt,            // [2][256]
    const float* __restrict__ bt,            // [2]
    float* __restrict__ out)                 // [2][32768]
{
  __shared__ __attribute__((aligned(16))) unsigned char smem[131072]; // buf0 | buf1 (buf1 doubles as A transient)
  __shared__ float gates_lds[64][17];
  __shared__ float red_lds[8][32][2];
  __shared__ float be_lds[2048];             // [8][256]

  const int tid   = threadIdx.x;
  const int wave  = tid >> 6;
  const int lane  = tid & 63;
  const int row16 = lane & 15;
  const int kgrp  = lane >> 4;
  const int wm    = wave >> 2;   // 0..1
  const int wn    = wave & 3;    // 0..3
  const int b0    = blockIdx.x * 64;

  unsigned char* buf0 = smem;
  unsigned char* bufA = smem + 65536;  // == buf1

  // ---- hoisted stage addressing: element offset into WeT (per i) ----
  unsigned soff[8];
#pragma unroll
  for (int i = 0; i < 8; ++i) {
    unsigned x = (unsigned)(i * 8192 + tid * 16);
    unsigned r = x >> 8;
    unsigned y = (x & 255u) ^ ((r & 15u) << 4);
    soff[i] = r * 512u + (y >> 1);     // pre-swizzled source element offset
  }

  // ---- prologue: stage(0) -> buf0 ----
#pragma unroll
  for (int i = 0; i < 8; ++i)
    GLOAD16(WeT + soff[i], buf0 + (i * 8 + wave) * 1024);

  // ---- A tile (64 x 512) fp32->bf16 into bufA, swizzled (byte ^= (r&7)<<4) ----
  // Non-temporal: xv is stream-once; do NOT let it evict WeT from L2.
#pragma unroll
  for (int i = 0; i < 8; ++i) {
    int idx = i * 512 + tid;
    int r = idx >> 6, c = idx & 63;
    const f32x4* src = reinterpret_cast<const f32x4*>(xv + (size_t)(b0 + r) * 512 + c * 8);
    f32x4 v0 = __builtin_nontemporal_load(src);
    f32x4 v1 = __builtin_nontemporal_load(src + 1);
    short8 pk;
    pk[0] = (short)f2bf(v0[0]); pk[1] = (short)f2bf(v0[1]);
    pk[2] = (short)f2bf(v0[2]); pk[3] = (short)f2bf(v0[3]);
    pk[4] = (short)f2bf(v1[0]); pk[5] = (short)f2bf(v1[1]);
    pk[6] = (short)f2bf(v1[2]); pk[7] = (short)f2bf(v1[3]);
    unsigned addr = ((unsigned)(r << 10) + (unsigned)(c << 4)) ^ (unsigned)((r & 7) << 4);
    *reinterpret_cast<short8*>(&bufA[addr]) = pk;
  }

  // be -> LDS (epilogue reads via lgkm; keeps main-loop vmcnt math exact)
#pragma unroll
  for (int j = 0; j < 4; ++j) {
    int idx = j * 512 + tid;
    be_lds[idx] = be[idx];
  }

  __syncthreads();   // full drain: stage(0) + A writes + be done (one-time)

  // ---- gates: waves 0..3 compute m-frag `wave`; softmax over experts ----
  if (wave < 4) {
    floatx4 gacc = {0.f, 0.f, 0.f, 0.f};
    const unsigned abase = ((unsigned)row16 << 10) + ((unsigned)kgrp << 4) + ((unsigned)wave << 14);
    const unsigned a_swz = (unsigned)((row16 & 7) << 4);
    const unsigned short* wg_lane = WgT + row16 * 512 + kgrp * 8;
#pragma unroll
    for (int ks = 0; ks < 16; ++ks) {
      short8 af = *reinterpret_cast<const short8*>(&bufA[(abase + (unsigned)(ks << 6)) ^ a_swz]);
      short8 bf = *reinterpret_cast<const short8*>(wg_lane + ks * 32);
      gacc = __builtin_amdgcn_mfma_f32_16x16x32_bf16(af, bf, gacc, 0, 0, 0);
    }
    float bgv = bg[row16];
#pragma unroll
    for (int j = 0; j < 4; ++j) {
      float v = gacc[j] + bgv;
      float mx = v;
      mx = fmaxf(mx, __shfl_xor(mx, 1));
      mx = fmaxf(mx, __shfl_xor(mx, 2));
      mx = fmaxf(mx, __shfl_xor(mx, 4));
      float p = __expf(v - mx);
      float s = p;
      s += __shfl_xor(s, 1);
      s += __shfl_xor(s, 2);
      s += __shfl_xor(s, 4);
      gates_lds[wave * 16 + kgrp * 4 + j][row16] = p / s;
    }
  }

  // ---- A-reg fill: 2 m-frags x 16 k-chunks per lane (128 VGPRs) ----
  short8 a_reg[2][16];
  {
    const unsigned a_swz = (unsigned)((row16 & 7) << 4);
#pragma unroll
    for (int m2 = 0; m2 < 2; ++m2) {
      const unsigned rbase = (unsigned)((wm * 2 + m2) * 16 + row16) << 10;
#pragma unroll
      for (int c = 0; c < 16; ++c)
        a_reg[m2][c] = *reinterpret_cast<const short8*>(
            &bufA[rbase + (((unsigned)(c << 6) + ((unsigned)kgrp << 4)) ^ a_swz)]);
    }
  }

  float wtv[2][4];
#pragma unroll
  for (int t = 0; t < 2; ++t)
#pragma unroll
    for (int n = 0; n < 4; ++n)
      wtv[t][n] = Wt[t * 256 + wn * 64 + n * 16 + row16];

  __syncthreads();   // A-reg fill + gates done; bufA free as B buffer

  // ---- main loop: 32 phases (8e x 4kc); counted vmcnt, 2 barriers/phase ----
  float outacc[2][4][2];
#pragma unroll
  for (int m = 0; m < 2; ++m)
#pragma unroll
    for (int j = 0; j < 4; ++j) { outacc[m][j][0] = 0.f; outacc[m][j][1] = 0.f; }

  const unsigned b_swz = (unsigned)(row16 << 4);
  const unsigned b_col = (unsigned)(wn * 64 + row16);

  for (int e = 0; e < 8; ++e) {
    floatx4 acc[2][4];
#pragma unroll
    for (int m = 0; m < 2; ++m)
#pragma unroll
      for (int n = 0; n < 4; ++n) acc[m][n] = (floatx4){0.f, 0.f, 0.f, 0.f};

#pragma unroll
    for (int kc = 0; kc < 4; ++kc) {
      const int p = e * 4 + kc;
      // 1. issue stage(p+1) into buf[(p+1)&1]
      if (p < 31) {
        unsigned char* sbuf = (p & 1) ? buf0 : bufA;
        const int ne  = (kc < 3) ? e : e + 1;
        const int nkc = (kc + 1) & 3;
        const unsigned short* base = WeT + (ne * 131072 + nkc * 128);  // k-chunk = 128 elements
#pragma unroll
        for (int i = 0; i < 8; ++i)
          GLOAD16(base + soff[i], sbuf + (i * 8 + wave) * 1024);
        asm volatile("s_waitcnt vmcnt(8)" ::: "memory");   // own stage(p) done; stage(p+1) in flight
      } else {
        asm volatile("s_waitcnt vmcnt(0)" ::: "memory");   // final phase
      }
      __builtin_amdgcn_s_barrier();                        // all waves' stage(p) complete
      __builtin_amdgcn_sched_barrier(0);                   // keep ds_reads below the barrier

      // 2. consume buf[p&1]
      const unsigned char* cb = (p & 1) ? bufA : buf0;
      __builtin_amdgcn_s_setprio(1);
#pragma unroll
      for (int ks = 0; ks < 4; ++ks) {
        short8 bfv[4];
#pragma unroll
        for (int n = 0; n < 4; ++n) {
          unsigned col = b_col + (unsigned)(n * 16);
          unsigned kb  = ((unsigned)(ks * 64 + kgrp * 16)) ^ b_swz;
          bfv[n] = *reinterpret_cast<const short8*>(&cb[col * 256 + kb]);
        }
#pragma unroll
        for (int m2 = 0; m2 < 2; ++m2)
#pragma unroll
          for (int n = 0; n < 4; ++n)
            acc[m2][n] = __builtin_amdgcn_mfma_f32_16x16x32_bf16(
                a_reg[m2][kc * 4 + ks], bfv[n], acc[m2][n], 0, 0, 0);
      }
      __builtin_amdgcn_s_setprio(0);
      __builtin_amdgcn_s_barrier();                        // all reads of buf[p&1] done
    }

    // ---- expert epilogue: bias+relu -> Wt-dot -> gate-weighted accumulate (LDS only) ----
    float bev[4];
#pragma unroll
    for (int n = 0; n < 4; ++n)
      bev[n] = be_lds[e * 256 + wn * 64 + n * 16 + row16];

#pragma unroll
    for (int m2 = 0; m2 < 2; ++m2) {
#pragma unroll
      for (int j = 0; j < 4; ++j) {
        int row = (wm * 2 + m2) * 16 + kgrp * 4 + j;
        float p0 = 0.f, p1 = 0.f;
#pragma unroll
        for (int n = 0; n < 4; ++n) {
          float r = fmaxf(acc[m2][n][j] + bev[n], 0.f);
          p0 = fmaf(r, wtv[0][n], p0);
          p1 = fmaf(r, wtv[1][n], p1);
        }
        outacc[m2][j][0] = fmaf(gates_lds[row][e],     p0, outacc[m2][j][0]);
        outacc[m2][j][1] = fmaf(gates_lds[row][8 + e], p1, outacc[m2][j][1]);
      }
    }
  }

  // ---- reduce over 16 col-lanes, then across the 4 n-waves via LDS ----
#pragma unroll
  for (int m = 0; m < 2; ++m)
#pragma unroll
    for (int j = 0; j < 4; ++j)
#pragma unroll
      for (int t = 0; t < 2; ++t) {
        float v = outacc[m][j][t];
        v += __shfl_xor(v, 1);
        v += __shfl_xor(v, 2);
        v += __shfl_xor(v, 4);
        v += __shfl_xor(v, 8);
        outacc[m][j][t] = v;
      }
  if (row16 == 0) {
#pragma unroll
    for (int m = 0; m < 2; ++m)
#pragma unroll
      for (int j = 0; j < 4; ++j) {
        int lr = m * 16 + kgrp * 4 + j;
        red_lds[wave][lr][0] = outacc[m][j][0];
        red_lds[wave][lr][1] = outacc[m][j][1];
      }
  }
  __syncthreads();

  if (tid < 128) {
    int row = tid >> 1, t = tid & 1;
    int wmr = row >> 5, lr = row & 31;
    float s = red_lds[wmr * 4 + 0][lr][t] + red_lds[wmr * 4 + 1][lr][t]
            + red_lds[wmr * 4 + 2][lr][t] + red_lds[wmr * 4 + 3][lr][t];
    s += bt[t];
    s = fmaxf(s, 0.f);
    out[t * BS + b0 + row] = 1.f / (1.f + __expf(-s));
  }
}

extern "C" void kernel_launch(void* const* d_in, const int* in_sizes, int n_in,
                              void* d_out, int out_size, void* d_ws, size_t ws_size,
                              hipStream_t stream) {
  const float* xv = (const float*)d_in[0];
  const float* We = (const float*)d_in[1];
  const float* be = (const float*)d_in[2];
  const float* Wg = (const float*)d_in[3];
  const float* bg = (const float*)d_in[4];
  const float* Wt = (const float*)d_in[5];
  const float* bt = (const float*)d_in[6];
  float* out = (float*)d_out;

  unsigned short* WeT = (unsigned short*)d_ws;            // 2 MiB
  unsigned short* WgT = WeT + 8 * 256 * 512;              // 16 KiB

  prep_weT<<<512, 256, 0, stream>>>(We, WeT);
  prep_wgT<<<16, 64, 0, stream>>>(Wg, WgT);
  mmoe_main<<<512, 512, 0, stream>>>(xv, WeT, WgT, be, bg, Wt, bt, out);
}